// Round 8
// baseline (312.850 us; speedup 1.0000x reference)
//
#include <hip/hip_runtime.h>
#include <math.h>

typedef unsigned short u16;
typedef __attribute__((ext_vector_type(8))) short bf16x8;
typedef __attribute__((ext_vector_type(4))) float f32x4;

#define D_MODEL 256
#define T_SZ 1024
constexpr size_t S_ELT = (size_t)8192 * 256;
constexpr size_t MB = 1024 * 1024;

// workspace byte offsets -- all disjoint
constexpr size_t OFF_QK = 0;             // u16 [8192][512] Q|K (8MB)
constexpr size_t OFF_VT = 8 * MB;        // u16 [32][64][1024] V^T (4MB)
constexpr size_t OFF_ATTN = 12 * MB;     // u16 [8192][256] (4MB)
constexpr size_t OFF_X = 16 * MB;        // f32 [8192][256] (8MB)
constexpr size_t OFF_XBF = 24 * MB;      // u16 [8192][256] (4MB)
constexpr size_t OFF_COMB = 28 * MB;     // u16 [8192][512] conv|ema (8MB)
constexpr size_t OFF_H = 36 * MB;        // u16 [8192][512] (8MB)
constexpr size_t OFF_FB = 44 * MB;       // f32 [8192][256] attn_out/deltas/ffn_out (8MB)
constexpr size_t OFF_STATES = 52 * MB;   // u16 [8192][256] (4MB)
constexpr size_t OFF_F = 56 * MB;        // u16 [8192][1024] (16MB)
constexpr size_t OFF_PRBF = 72 * MB;     // u16 [8192][256] (4MB)
constexpr size_t OFF_WB = 76 * MB;       // u16 weights (2.75MB)
constexpr size_t OFF_P2ST = 79 * MB;               // u16 [320][256] (160KB)
constexpr size_t OFF_S2PT = 79 * MB + 163840;      // u16 [320][256]
constexpr size_t OFF_W1X = 80 * MB;                // u16 [512][256] (256KB)
constexpr size_t OFF_W1S = 80 * MB + 262144;       // u16 [1024][256] (512KB)
constexpr size_t OFF_B1X = 81 * MB;                // f32 [512]
constexpr size_t OFF_B1S = 81 * MB + 4096;         // f32 [1024]
constexpr size_t OFF_SCR = 82 * MB;                // f32 65536 (ema raw, then cs raw)

// bf16 weight element offsets inside WB
constexpr int WB_INPROJ = 0;
constexpr int WB_OUTPROJ = 196608;
constexpr int WB_P2S = 262144;
constexpr int WB_S2P = 327680;
constexpr int WB_T1 = 393216;
constexpr int WB_T2 = 786432;
constexpr int WB_F1 = 917504;
constexpr int WB_F2 = 1179648;
constexpr int WB_TOTAL = 1441792;
constexpr int PR_TOTAL = 2097152;
constexpr int TR_TOTAL = 163840;  // p2sT_ext + s2pT_ext (2 x 320 x 256)

__device__ __forceinline__ u16 f2bf(float f) {
  unsigned int u = __float_as_uint(f);
  u += 0x7fff + ((u >> 16) & 1);
  return (u16)(u >> 16);
}
__device__ __forceinline__ float bf2f(u16 s) {
  return __uint_as_float(((unsigned int)s) << 16);
}

// async global -> LDS, 16B per lane; LDS dst is wave-uniform base + lane*16B.
__device__ __forceinline__ void glds16(const u16* g, u16* l) {
  __builtin_amdgcn_global_load_lds(
      (const __attribute__((address_space(1))) void*)g,
      (__attribute__((address_space(3))) void*)l, 16, 0, 0);
}

__device__ __forceinline__ float block_reduce_sum(float v, float* tmp) {
#pragma unroll
  for (int o = 32; o > 0; o >>= 1) v += __shfl_down(v, o);
  const int lane = threadIdx.x & 63, wid = threadIdx.x >> 6;
  if (lane == 0) tmp[wid] = v;
  __syncthreads();
  v = tmp[0] + tmp[1] + tmp[2] + tmp[3];
  __syncthreads();
  return v;
}

// ---------------------------------------------------------------------------
// weights + parallel_repr -> bf16; also emits p2sT_ext/s2pT_ext [320][256]
// (rows 0:256 = transpose, row 256 = bias vector, rows 257:320 = zero pad)
// ---------------------------------------------------------------------------
__global__ __launch_bounds__(256)
void wconv_kernel(const float* w0, const float* w1, const float* w2,
                  const float* w3, const float* w4, const float* w5,
                  const float* w6, const float* w7, const float* pr,
                  const float* p2sb, const float* s2pb, u16* __restrict__ wb,
                  u16* __restrict__ prb, u16* __restrict__ p2sT,
                  u16* __restrict__ s2pT) {
  const int idx4 = (blockIdx.x * 256 + threadIdx.x) * 4;
  if (idx4 < WB_TOTAL) {
    const int offs[9] = {WB_INPROJ, WB_OUTPROJ, WB_P2S,  WB_S2P, WB_T1,
                         WB_T2,     WB_F1,      WB_F2,   WB_TOTAL};
    const float* srcs[8] = {w0, w1, w2, w3, w4, w5, w6, w7};
    int seg = 0;
    while (idx4 >= offs[seg + 1]) ++seg;
    float4 v = *(const float4*)(srcs[seg] + (idx4 - offs[seg]));
    unsigned int lo = (unsigned int)f2bf(v.x) | ((unsigned int)f2bf(v.y) << 16);
    unsigned int hi = (unsigned int)f2bf(v.z) | ((unsigned int)f2bf(v.w) << 16);
    *(uint2*)(wb + idx4) = make_uint2(lo, hi);
  } else if (idx4 < WB_TOTAL + PR_TOTAL) {
    const int i4 = idx4 - WB_TOTAL;
    float4 v = *(const float4*)(pr + i4);
    unsigned int lo = (unsigned int)f2bf(v.x) | ((unsigned int)f2bf(v.y) << 16);
    unsigned int hi = (unsigned int)f2bf(v.z) | ((unsigned int)f2bf(v.w) << 16);
    *(uint2*)(prb + i4) = make_uint2(lo, hi);
  } else {
    int e = idx4 - (WB_TOTAL + PR_TOTAL);
    if (e >= TR_TOTAL) return;
    const bool second = e >= (TR_TOTAL / 2);
    if (second) e -= TR_TOTAL / 2;
    const float* src = second ? w3 : w2;       // s2p : p2s
    const float* bias = second ? s2pb : p2sb;
    u16* dst = second ? s2pT : p2sT;
    const int j = e >> 8, k0 = e & 255;
    u16 h[4];
#pragma unroll
    for (int q = 0; q < 4; ++q) {
      const int k = k0 + q;
      float v = 0.f;
      if (j < 256) v = src[k * 256 + j];
      else if (j == 256) v = bias[k];
      h[q] = f2bf(v);
    }
    unsigned int lo = (unsigned int)h[0] | ((unsigned int)h[1] << 16);
    unsigned int hi = (unsigned int)h[2] | ((unsigned int)h[3] << 16);
    *(uint2*)(dst + e) = make_uint2(lo, hi);
  }
}

// ---------------------------------------------------------------------------
// MFMA weight fold (one dispatch, grid (24,5)):
//  bx<8 : W1x[n][i]  = t1a[n][i] + 0.3*sum_c t1a[n][c]*p2s[c][i]   (n<512)
//         b1x[n]     = trans_b1[n] + 0.3*sum_c t1a[n][c]*p2s_b[c]  (col 256)
//  bx>=8: W1s[m][c]  = 0.3*sum_i f1[m][i]*s2p[i][c]                (m<1024)
//         b1s[m]     = ffn_b1[m] + 0.3*sum_i f1[m][i]*s2p_b[i]
// ---------------------------------------------------------------------------
__global__ __launch_bounds__(256, 4)
void wfold_mfma(const u16* __restrict__ wb, const u16* __restrict__ p2sT,
                const u16* __restrict__ s2pT, const float* __restrict__ tb1,
                const float* __restrict__ fb1, u16* __restrict__ w1x,
                u16* __restrict__ w1s, float* __restrict__ b1x,
                float* __restrict__ b1s) {
  __shared__ u16 As[64 * 64];
  __shared__ u16 Bs[64 * 64];
  const int tid = threadIdx.x;
  const int w = tid >> 6, lane = tid & 63;
  const int ln = lane & 15, quad = lane >> 4;
  const bool m1 = blockIdx.x >= 8;
  const int m0 = (m1 ? (blockIdx.x - 8) : blockIdx.x) * 64;
  const int n0 = blockIdx.y * 64;
  const u16* A = m1 ? (wb + WB_F1) : (wb + WB_T1);
  const int lda = m1 ? 256 : 768;
  const u16* B = m1 ? s2pT : p2sT;
  const float* tb = m1 ? fb1 : tb1;
  u16* wout = m1 ? w1s : w1x;
  float* bout = m1 ? b1s : b1x;
  const int wm = w * 16;
  f32x4 acc[4] = {};
  const int grow = lane >> 2, gk8 = (lane & 3) * 8;

  for (int k0 = 0; k0 < 256; k0 += 64) {
#pragma unroll
    for (int s = 0; s < 2; ++s) {
      glds16(A + (size_t)(m0 + w * 16 + grow) * lda + k0 + s * 32 + gk8,
             As + s * 2048 + w * 512);
      glds16(B + (size_t)(n0 + w * 16 + grow) * 256 + k0 + s * 32 + gk8,
             Bs + s * 2048 + w * 512);
    }
    __syncthreads();
#pragma unroll
    for (int s = 0; s < 2; ++s) {
      bf16x8 af = *(const bf16x8*)(As + s * 2048 + w * 512 + ln * 32 + quad * 8);
#pragma unroll
      for (int j = 0; j < 4; ++j) {
        bf16x8 bv = *(const bf16x8*)(Bs + s * 2048 + j * 512 + ln * 32 + quad * 8);
        acc[j] = __builtin_amdgcn_mfma_f32_16x16x32_bf16(af, bv, acc[j], 0, 0, 0);
      }
    }
    __syncthreads();
  }
#pragma unroll
  for (int j = 0; j < 4; ++j) {
    const int col = n0 + j * 16 + ln;
    const int row0 = m0 + wm + quad * 4;
    if (col < 256) {
#pragma unroll
      for (int r = 0; r < 4; ++r) {
        float add = m1 ? 0.f : bf2f(wb[WB_T1 + (size_t)(row0 + r) * 768 + col]);
        wout[(size_t)(row0 + r) * 256 + col] = f2bf(add + 0.3f * acc[j][r]);
      }
    } else if (col == 256) {
#pragma unroll
      for (int r = 0; r < 4; ++r)
        bout[row0 + r] = tb[row0 + r] + 0.3f * acc[j][r];
    }
  }
}

// ---------------------------------------------------------------------------
// bf16 MFMA GEMM, fragment-ordered async LDS staging, BK=64.
// A and W may be split at k=ksplit. VSPLIT: cols>=512 transposed to vt.
// ---------------------------------------------------------------------------
enum { EPI_NONE = 0, EPI_GELU = 1 };

template <int EPI, int BM, int BN, bool OUTBF, bool VSPLIT>
__global__ __launch_bounds__(256, 4)
void mgemm(const u16* __restrict__ A1, int lda1, const u16* __restrict__ A2,
           int lda2, int ksplit, const u16* __restrict__ W1, int ldw1,
           const u16* __restrict__ W2, int ldw2, int woff2, int K,
           const float* __restrict__ bias, void* __restrict__ Cv, int ldc,
           u16* __restrict__ vt) {
  __shared__ u16 As[BM * 64];
  __shared__ u16 Bs[BN * 64];
  const int tid = threadIdx.x;
  const int w = tid >> 6, lane = tid & 63;
  const int ln = lane & 15, quad = lane >> 4;
  const int m0 = blockIdx.x * BM;
  const int n0 = blockIdx.y * BN;
  constexpr int MT = BM / 64;
  constexpr int NT = BN / 16;
  const int wm = w * (MT * 16);
  constexpr int APW = BM / 64;
  constexpr int BPW = BN / 64;

  f32x4 acc[MT][NT] = {};

  const int grow = lane >> 2;
  const int gk8 = (lane & 3) * 8;

  for (int k0 = 0; k0 < K; k0 += 64) {
#pragma unroll
    for (int s = 0; s < 2; ++s) {
      const int kb = k0 + s * 32;
      const bool r1 = kb < ksplit;
      const u16* Ab = r1 ? A1 : A2;
      const int alda = r1 ? lda1 : lda2;
      const int ak = r1 ? kb : kb - ksplit;
#pragma unroll
      for (int p = 0; p < APW; ++p) {
        const int g = w * APW + p;
        glds16(Ab + (size_t)(m0 + g * 16 + grow) * alda + ak + gk8,
               As + s * BM * 32 + g * 512);
      }
      const u16* Wb = r1 ? W1 : W2;
      const int wlda = r1 ? ldw1 : ldw2;
      const int wk = r1 ? kb : kb - woff2;
#pragma unroll
      for (int p = 0; p < BPW; ++p) {
        const int g = w * BPW + p;
        glds16(Wb + (size_t)(n0 + g * 16 + grow) * wlda + wk + gk8,
               Bs + s * BN * 32 + g * 512);
      }
    }
    __syncthreads();
#pragma unroll
    for (int s = 0; s < 2; ++s) {
      const u16* abase = As + s * BM * 32 + (wm >> 4) * 512 + ln * 32 + quad * 8;
      const u16* bbase = Bs + s * BN * 32 + ln * 32 + quad * 8;
      bf16x8 af[MT], bv[NT];
#pragma unroll
      for (int i = 0; i < MT; ++i) af[i] = *(const bf16x8*)(abase + i * 512);
#pragma unroll
      for (int j = 0; j < NT; ++j) bv[j] = *(const bf16x8*)(bbase + j * 512);
#pragma unroll
      for (int i = 0; i < MT; ++i)
#pragma unroll
        for (int j = 0; j < NT; ++j)
          acc[i][j] = __builtin_amdgcn_mfma_f32_16x16x32_bf16(af[i], bv[j],
                                                              acc[i][j], 0, 0, 0);
    }
    __syncthreads();
  }

#pragma unroll
  for (int i = 0; i < MT; ++i)
#pragma unroll
    for (int j = 0; j < NT; ++j) {
      const int col = n0 + j * 16 + ln;
      const float bsv = bias[col];
      const int row0 = m0 + wm + i * 16 + quad * 4;
      float vals[4];
#pragma unroll
      for (int r = 0; r < 4; ++r) {
        float v = acc[i][j][r] + bsv;
        if (EPI == EPI_GELU) v = 0.5f * v * (1.0f + erff(v * 0.70710678f));
        vals[r] = v;
      }
      if (VSPLIT && col >= 512) {
        ushort4 pk;
        pk.x = f2bf(vals[0]); pk.y = f2bf(vals[1]);
        pk.z = f2bf(vals[2]); pk.w = f2bf(vals[3]);
        *(ushort4*)(vt + (size_t)((row0 >> 10) * 256 + (col - 512)) * T_SZ +
                    (row0 & 1023)) = pk;
      } else if (OUTBF) {
#pragma unroll
        for (int r = 0; r < 4; ++r)
          ((u16*)Cv)[(size_t)(row0 + r) * ldc + col] = f2bf(vals[r]);
      } else {
#pragma unroll
        for (int r = 0; r < 4; ++r)
          ((float*)Cv)[(size_t)(row0 + r) * ldc + col] = vals[r];
      }
    }
}

// ---------------------------------------------------------------------------
// Barrier-free MFMA flash attention (one wave = 16 q rows, paired balance).
// ---------------------------------------------------------------------------
__global__ __launch_bounds__(256)
void attn_flash(const u16* __restrict__ qk, const u16* __restrict__ vt,
                u16* __restrict__ outp) {
  __shared__ u16 Ps[4][16][72];
  const int tid = threadIdx.x;
  const int w = tid >> 6, lane = tid & 63;
  const int ln = lane & 15, quad = lane >> 4, kq8 = quad * 8;
  const int wu = blockIdx.x * 4 + w;
  const int bh = wu >> 6, s = wu & 63;
  const int qt = (s & 1) ? (63 - (s >> 1)) : (s >> 1);
  const int q0 = qt * 16;
  const int b = bh >> 2, h = bh & 3;
  const u16* base = qk + (size_t)b * T_SZ * 512;
  const u16* vbase = vt + (size_t)bh * 64 * T_SZ;

  bf16x8 qf[2];
#pragma unroll
  for (int ks = 0; ks < 2; ++ks)
    qf[ks] = *(const bf16x8*)(base + (size_t)(q0 + ln) * 512 + h * 64 +
                              ks * 32 + kq8);
  const short ob = (short)0x3F80;
  const bf16x8 ones = {ob, ob, ob, ob, ob, ob, ob, ob};

  f32x4 O[4] = {};
  f32x4 l_acc = {};
  const int ntiles = (qt >> 2) + 1;
  for (int jt = 0; jt < ntiles; ++jt) {
    const int c0 = jt * 64;
    f32x4 sv[4] = {};
#pragma unroll
    for (int ks = 0; ks < 2; ++ks)
#pragma unroll
      for (int j = 0; j < 4; ++j) {
        bf16x8 kf = *(const bf16x8*)(base + (size_t)(c0 + j * 16 + ln) * 512 +
                                     256 + h * 64 + ks * 32 + kq8);
        sv[j] = __builtin_amdgcn_mfma_f32_16x16x32_bf16(qf[ks], kf, sv[j], 0, 0, 0);
      }
    const bool need_mask = (c0 + 63 > q0);
#pragma unroll
    for (int j = 0; j < 4; ++j)
#pragma unroll
      for (int r = 0; r < 4; ++r) {
        float p = __expf(sv[j][r] * 0.125f);
        if (need_mask && (c0 + j * 16 + ln > q0 + quad * 4 + r)) p = 0.f;
        Ps[w][quad * 4 + r][j * 16 + ln] = f2bf(p);
      }
#pragma unroll
    for (int ks = 0; ks < 2; ++ks) {
      bf16x8 pf = *(const bf16x8*)&Ps[w][ln][ks * 32 + kq8];
      l_acc = __builtin_amdgcn_mfma_f32_16x16x32_bf16(pf, ones, l_acc, 0, 0, 0);
#pragma unroll
      for (int j = 0; j < 4; ++j) {
        bf16x8 vf = *(const bf16x8*)(vbase + (size_t)(j * 16 + ln) * T_SZ +
                                     c0 + ks * 32 + kq8);
        O[j] = __builtin_amdgcn_mfma_f32_16x16x32_bf16(pf, vf, O[j], 0, 0, 0);
      }
    }
  }
  u16* op = outp + (size_t)b * T_SZ * 256;
#pragma unroll
  for (int r = 0; r < 4; ++r) {
    const float inv = 1.f / l_acc[r];
#pragma unroll
    for (int j = 0; j < 4; ++j)
      op[(size_t)(q0 + quad * 4 + r) * 256 + h * 64 + j * 16 + ln] =
          f2bf(O[j][r] * inv);
  }
}

// ---------------------------------------------------------------------------
__device__ __forceinline__ float ln_finish(float v, float s1, float s2,
                                           float g, float bb) {
  float mean = s1 * (1.f / 256.f);
  float var = s2 * (1.f / 256.f) - mean * mean;
  return (v - mean) * rsqrtf(var + 1e-5f) * g + bb;
}

__global__ __launch_bounds__(256)
void ln_add_kernel(const float* __restrict__ a, const float* __restrict__ addsrc,
                   const float* __restrict__ g, const float* __restrict__ bb,
                   float* __restrict__ outp, u16* __restrict__ obf) {
  __shared__ float tmp[4];
  const size_t row = blockIdx.x;
  const int d = threadIdx.x;
  float v = a[row * 256 + d] + addsrc[row * 256 + d];
  float s1 = block_reduce_sum(v, tmp);
  float s2 = block_reduce_sum(v * v, tmp);
  float y = ln_finish(v, s1, s2, g[d], bb[d]);
  outp[row * 256 + d] = y;
  if (obf) obf[row * 256 + d] = f2bf(y);
}

// states = LN3(seq + 0.5*(local_cumsum + carry)); carry computed from raw
// chunk sums in scr. t==1023 also applies LN4 -> fss.
__global__ __launch_bounds__(256)
void ln34_kernel(const float* __restrict__ deltas, const float* __restrict__ scr,
                 const float* __restrict__ seq, const float* __restrict__ g3,
                 const float* __restrict__ b3, const float* __restrict__ g4,
                 const float* __restrict__ b4, u16* __restrict__ st,
                 float* __restrict__ fss) {
  __shared__ float tmp[4];
  const int row = blockIdx.x;
  const int b = row >> 10, t = row & 1023;
  const int d = threadIdx.x;
  const int ch = t >> 5;
  float carry = 0.f;
  for (int j = 0; j < ch; ++j)
    carry += scr[(size_t)(b * 32 + j) * 256 + d];
  float v = seq[b * 256 + d] +
            0.5f * (deltas[(size_t)row * 256 + d] + carry);
  float s1 = block_reduce_sum(v, tmp);
  float s2 = block_reduce_sum(v * v, tmp);
  float y = ln_finish(v, s1, s2, g3[d], b3[d]);
  st[(size_t)row * 256 + d] = f2bf(y);
  if (t == 1023) {
    float t1s = block_reduce_sum(y, tmp);
    float t2s = block_reduce_sum(y * y, tmp);
    fss[b * 256 + d] = ln_finish(y, t1s, t2s, g4[d], b4[d]);
  }
}

// ---------------------------------------------------------------------------
// Fused depthwise conv (window 8) + EMA local pass. comb [8192][512]:
// cols 0:256 conv, 256:512 local EMA. scr = raw chunk-end EMA values.
// ---------------------------------------------------------------------------
__global__ __launch_bounds__(256)
void emaconv_kernel(const float* __restrict__ x, const float* __restrict__ cw,
                    const float* __restrict__ cb, u16* __restrict__ comb,
                    float* __restrict__ scr) {
  const int bc = blockIdx.x;
  const int b = bc >> 5, ch = bc & 31;
  const int d = threadIdx.x;
  const int t0 = ch * 32;
  float wreg[8];
#pragma unroll
  for (int j = 0; j < 8; ++j) wreg[j] = cw[d * 8 + j];
  const float bias = cb[d];
  float xw[8];
#pragma unroll
  for (int j = 0; j < 7; ++j) {
    const int ts = t0 - 7 + j;
    xw[j] = (ts >= 0) ? x[(size_t)(b * T_SZ + ts) * 256 + d] : 0.f;
  }
  float c = 0.f;
#pragma unroll
  for (int tl = 0; tl < 32; ++tl) {
    const size_t row = (size_t)(b * T_SZ + t0 + tl);
    xw[7] = x[row * 256 + d];
    float conv = bias;
#pragma unroll
    for (int j = 0; j < 8; ++j) conv = fmaf(xw[j], wreg[j], conv);
    c = 0.9f * c + 0.1f * xw[7];
    comb[row * 512 + d] = f2bf(conv);
    comb[row * 512 + 256 + d] = f2bf(c);
#pragma unroll
    for (int j = 0; j < 7; ++j) xw[j] = xw[j + 1];
  }
  scr[(size_t)bc * 256 + d] = c;
}

// applies cross-chunk EMA carry (computed from raw scr values) + fts out
__global__ __launch_bounds__(256)
void ema_c_kernel(u16* __restrict__ comb, const float* __restrict__ scr,
                  float* __restrict__ fts) {
  const int row = blockIdx.x;
  const int b = row >> 10, t = row & 1023;
  const int d = threadIdx.x;
  const int ch = t >> 5, tl = t & 31;
  const float q32 = 0.03433683820292512f;  // 0.9^32
  float carry = 0.f;
  for (int j = 0; j < ch; ++j)
    carry = q32 * carry + scr[(size_t)(b * 32 + j) * 256 + d];
  float l = bf2f(comb[(size_t)row * 512 + 256 + d]);
  float y = fmaf(__powf(0.9f, (float)(tl + 1)), carry, l);
  comb[(size_t)row * 512 + 256 + d] = f2bf(y);
  if (t == 1023) fts[b * 256 + d] = y;
}

__global__ __launch_bounds__(256)
void cs_a_kernel(float* __restrict__ deltas, float* __restrict__ scr) {
  const int bc = blockIdx.x;
  const int b = bc >> 5, ch = bc & 31;
  const int d = threadIdx.x;
  const int t0 = ch * 32;
  float c = 0.f;
  for (int tl = 0; tl < 32; ++tl) {
    const size_t idx = (size_t)(b * T_SZ + t0 + tl) * 256 + d;
    c += deltas[idx];
    deltas[idx] = c;
  }
  scr[(size_t)bc * 256 + d] = c;
}

// ---------------------------------------------------------------------------
extern "C" void kernel_launch(void* const* d_in, const int* in_sizes, int n_in,
                              void* d_out, int out_size, void* d_ws,
                              size_t ws_size, hipStream_t stream) {
  (void)in_sizes; (void)n_in; (void)out_size; (void)ws_size;
  const float* parallel_repr = (const float*)d_in[0];
  const float* sequential_state = (const float*)d_in[1];
  const float* in_proj_b = (const float*)d_in[4];
  const float* out_proj_b = (const float*)d_in[6];
  const float* conv_w = (const float*)d_in[7];
  const float* conv_b = (const float*)d_in[8];
  const float* p2s_b = (const float*)d_in[10];
  const float* s2p_b = (const float*)d_in[12];
  const float* trans_b1 = (const float*)d_in[14];
  const float* trans_b2 = (const float*)d_in[16];
  const float* ffn_b1 = (const float*)d_in[18];
  const float* ffn_b2 = (const float*)d_in[20];
  const float* ln1_s = (const float*)d_in[21];
  const float* ln1_b = (const float*)d_in[22];
  const float* ln2_s = (const float*)d_in[23];
  const float* ln2_b = (const float*)d_in[24];
  const float* ln3_s = (const float*)d_in[25];
  const float* ln3_b = (const float*)d_in[26];
  const float* ln4_s = (const float*)d_in[27];
  const float* ln4_b = (const float*)d_in[28];

  char* ws = (char*)d_ws;
  u16* qk_bf = (u16*)(ws + OFF_QK);
  u16* vt = (u16*)(ws + OFF_VT);
  u16* attn_bf = (u16*)(ws + OFF_ATTN);
  float* x = (float*)(ws + OFF_X);
  u16* x_bf = (u16*)(ws + OFF_XBF);
  u16* comb = (u16*)(ws + OFF_COMB);
  u16* h_bf = (u16*)(ws + OFF_H);
  float* fbuf = (float*)(ws + OFF_FB);
  u16* states_bf = (u16*)(ws + OFF_STATES);
  u16* f_bf = (u16*)(ws + OFF_F);
  u16* pr_bf = (u16*)(ws + OFF_PRBF);
  u16* wb = (u16*)(ws + OFF_WB);
  u16* p2sT = (u16*)(ws + OFF_P2ST);
  u16* s2pT = (u16*)(ws + OFF_S2PT);
  u16* w1x = (u16*)(ws + OFF_W1X);
  u16* w1s = (u16*)(ws + OFF_W1S);
  float* b1x = (float*)(ws + OFF_B1X);
  float* b1s = (float*)(ws + OFF_B1S);
  float* scr = (float*)(ws + OFF_SCR);
  float* out = (float*)d_out;
  float* out_fss = out + S_ELT;
  float* out_fts = out + S_ELT + 2048;

  const dim3 blk(256);

  // 0. weights + parallel_repr -> bf16; p2sT/s2pT panels
  wconv_kernel<<<3617, blk, 0, stream>>>(
      (const float*)d_in[3], (const float*)d_in[5], (const float*)d_in[9],
      (const float*)d_in[11], (const float*)d_in[13], (const float*)d_in[15],
      (const float*)d_in[17], (const float*)d_in[19], parallel_repr, p2s_b,
      s2p_b, wb, pr_bf, p2sT, s2pT);
  // 1. MFMA weight fold: W1x/b1x (t1<-p2s), W1s/b1s (ffn1<-s2p)
  wfold_mfma<<<dim3(24, 5), blk, 0, stream>>>(wb, p2sT, s2pT, trans_b1, ffn_b1,
                                              w1x, w1s, b1x, b1s);
  // 2. qkv projection: Q,K -> qk; V transposed -> vt
  mgemm<EPI_NONE, 128, 64, true, true><<<dim3(64, 12), blk, 0, stream>>>(
      pr_bf, 256, pr_bf, 256, 256, wb + WB_INPROJ, 256, wb + WB_INPROJ, 256, 0,
      256, in_proj_b, qk_bf, 512, vt);
  // 3. attention (barrier-free)
  attn_flash<<<512, blk, 0, stream>>>(qk_bf, vt, attn_bf);
  // 4. attn_out = attn @ out_proj^T + b -> fbuf (fp32)
  mgemm<EPI_NONE, 64, 64, false, false><<<dim3(128, 4), blk, 0, stream>>>(
      attn_bf, 256, attn_bf, 256, 256, wb + WB_OUTPROJ, 256, wb + WB_OUTPROJ,
      256, 0, 256, out_proj_b, fbuf, 256, nullptr);
  // 5. x = LN1(PR + attn_out), also emit x_bf
  ln_add_kernel<<<8192, blk, 0, stream>>>(parallel_repr, fbuf, ln1_s, ln1_b, x,
                                          x_bf);
  // 6-7. fused conv+EMA -> comb; carry fixup + traj summary
  emaconv_kernel<<<256, blk, 0, stream>>>(x, conv_w, conv_b, comb, scr);
  ema_c_kernel<<<8192, blk, 0, stream>>>(comb, scr, out_fts);
  // 8. h = gelu([x | conv | ema] @ [W1x | t1bc]^T + b1x)
  mgemm<EPI_GELU, 128, 64, true, false><<<dim3(64, 8), blk, 0, stream>>>(
      x_bf, 256, comb, 512, 256, w1x, 256, wb + WB_T1, 768, 0, 768, b1x, h_bf,
      512, nullptr);
  // 9. deltas = h @ t2^T + b2 -> fbuf (fp32)
  mgemm<EPI_NONE, 64, 64, false, false><<<dim3(128, 4), blk, 0, stream>>>(
      h_bf, 512, h_bf, 512, 512, wb + WB_T2, 512, wb + WB_T2, 512, 0, 512,
      trans_b2, fbuf, 256, nullptr);
  // 10. chunk-local cumsum + chunk sums
  cs_a_kernel<<<256, blk, 0, stream>>>(fbuf, scr);
  // 11. states = LN3(...) (self-carry); fused LN4 -> out_fss
  ln34_kernel<<<8192, blk, 0, stream>>>(fbuf, scr, sequential_state, ln3_s,
                                        ln3_b, ln4_s, ln4_b, states_bf, out_fss);
  // 12. f = gelu([x | states] @ [ffn1 | W1s]^T + b1s)
  mgemm<EPI_GELU, 128, 64, true, false><<<dim3(64, 16), blk, 0, stream>>>(
      x_bf, 256, states_bf, 256, 256, wb + WB_F1, 256, w1s, 256, 256, 512, b1s,
      f_bf, 1024, nullptr);
  // 13. ffn_out = f @ ffn2^T + b2 -> fbuf
  mgemm<EPI_NONE, 64, 64, false, false><<<dim3(128, 4), blk, 0, stream>>>(
      f_bf, 1024, f_bf, 1024, 1024, wb + WB_F2, 1024, wb + WB_F2, 1024, 0,
      1024, ffn_b2, fbuf, 256, nullptr);
  // 14. out = LN2(x + ffn_out)
  ln_add_kernel<<<8192, blk, 0, stream>>>(x, fbuf, ln2_s, ln2_b, out, nullptr);
}

// Round 10
// 279.600 us; speedup vs baseline: 1.1189x; 1.1189x over previous
//
#include <hip/hip_runtime.h>
#include <math.h>

typedef unsigned short u16;
typedef __attribute__((ext_vector_type(8))) short bf16x8;
typedef __attribute__((ext_vector_type(4))) float f32x4;

#define D_MODEL 256
#define T_SZ 1024
constexpr size_t S_ELT = (size_t)8192 * 256;
constexpr size_t MB = 1024 * 1024;

// workspace byte offsets -- all disjoint (checked against lifetimes):
// QK 0-8 | VT 8-12 | ATTN 12-16 | X 16-24 | XBF 24-28 | COMB 28-36 |
// XP 36-40 | H 40-48 | FB 48-56 | STATES 56-60 | FFNIN 60-64 | F 64-80 |
// PRBF 80-84 | WB 84-87 | SCR 88-
constexpr size_t OFF_QK = 0;             // u16 [8192][512] Q|K (8MB)
constexpr size_t OFF_VT = 8 * MB;        // u16 [32][64][1024] V^T (4MB)
constexpr size_t OFF_ATTN = 12 * MB;     // u16 [8192][256] (4MB)
constexpr size_t OFF_X = 16 * MB;        // f32 [8192][256] (8MB)
constexpr size_t OFF_XBF = 24 * MB;      // u16 [8192][256] (4MB)
constexpr size_t OFF_COMB = 28 * MB;     // u16 [8192][512] conv|ema (8MB)
constexpr size_t OFF_XP = 36 * MB;       // u16 [8192][256] x+0.3*p2s (4MB)
constexpr size_t OFF_H = 40 * MB;        // u16 [8192][512] (8MB)
constexpr size_t OFF_FB = 48 * MB;       // f32 [8192][256] attn_out/deltas/ffn_out (8MB)
constexpr size_t OFF_STATES = 56 * MB;   // u16 [8192][256] (4MB)
constexpr size_t OFF_FFNIN = 60 * MB;    // u16 [8192][256] (4MB)
constexpr size_t OFF_F = 64 * MB;        // u16 [8192][1024] (16MB)
constexpr size_t OFF_PRBF = 80 * MB;     // u16 [8192][256] (4MB)
constexpr size_t OFF_WB = 84 * MB;       // u16 weights (2.75MB)
constexpr size_t OFF_SCR = 88 * MB;      // f32 65536 (ema carries, then cumsum)

// bf16 weight element offsets inside WB
constexpr int WB_INPROJ = 0;
constexpr int WB_OUTPROJ = 196608;
constexpr int WB_P2S = 262144;
constexpr int WB_S2P = 327680;
constexpr int WB_T1 = 393216;
constexpr int WB_T2 = 786432;
constexpr int WB_F1 = 917504;
constexpr int WB_F2 = 1179648;
constexpr int WB_TOTAL = 1441792;
constexpr int PR_TOTAL = 2097152;

__device__ __forceinline__ u16 f2bf(float f) {
  unsigned int u = __float_as_uint(f);
  u += 0x7fff + ((u >> 16) & 1);
  return (u16)(u >> 16);
}
__device__ __forceinline__ float bf2f(u16 s) {
  return __uint_as_float(((unsigned int)s) << 16);
}

// async global -> LDS, 16B per lane; LDS dst is wave-uniform base + lane*16B.
__device__ __forceinline__ void glds16(const u16* g, u16* l) {
  __builtin_amdgcn_global_load_lds(
      (const __attribute__((address_space(1))) void*)g,
      (__attribute__((address_space(3))) void*)l, 16, 0, 0);
}

__device__ __forceinline__ float block_reduce_sum(float v, float* tmp) {
#pragma unroll
  for (int o = 32; o > 0; o >>= 1) v += __shfl_down(v, o);
  const int lane = threadIdx.x & 63, wid = threadIdx.x >> 6;
  if (lane == 0) tmp[wid] = v;
  __syncthreads();
  v = tmp[0] + tmp[1] + tmp[2] + tmp[3];
  __syncthreads();
  return v;
}

// ---------------------------------------------------------------------------
// weight + parallel_repr fp32 -> bf16 conversion (single kernel)
// ---------------------------------------------------------------------------
__global__ __launch_bounds__(256)
void wconv_kernel(const float* w0, const float* w1, const float* w2,
                  const float* w3, const float* w4, const float* w5,
                  const float* w6, const float* w7, const float* pr,
                  u16* __restrict__ wb, u16* __restrict__ prb) {
  const int idx4 = (blockIdx.x * 256 + threadIdx.x) * 4;
  if (idx4 < WB_TOTAL) {
    const int offs[9] = {WB_INPROJ, WB_OUTPROJ, WB_P2S,  WB_S2P, WB_T1,
                         WB_T2,     WB_F1,      WB_F2,   WB_TOTAL};
    const float* srcs[8] = {w0, w1, w2, w3, w4, w5, w6, w7};
    int seg = 0;
    while (idx4 >= offs[seg + 1]) ++seg;
    float4 v = *(const float4*)(srcs[seg] + (idx4 - offs[seg]));
    unsigned int lo = (unsigned int)f2bf(v.x) | ((unsigned int)f2bf(v.y) << 16);
    unsigned int hi = (unsigned int)f2bf(v.z) | ((unsigned int)f2bf(v.w) << 16);
    *(uint2*)(wb + idx4) = make_uint2(lo, hi);
  } else {
    const int i4 = idx4 - WB_TOTAL;
    if (i4 < PR_TOTAL) {
      float4 v = *(const float4*)(pr + i4);
      unsigned int lo = (unsigned int)f2bf(v.x) | ((unsigned int)f2bf(v.y) << 16);
      unsigned int hi = (unsigned int)f2bf(v.z) | ((unsigned int)f2bf(v.w) << 16);
      *(uint2*)(prb + i4) = make_uint2(lo, hi);
    }
  }
}

// ---------------------------------------------------------------------------
// bf16 MFMA GEMM, fragment-ordered async LDS staging, BK=64.
// BN=32 supported (B staged by waves 0-1) for 2x grid / occupancy.
// A and W may be split at k=ksplit. VSPLIT: cols>=512 transposed to vt.
// ---------------------------------------------------------------------------
enum { EPI_NONE = 0, EPI_GELU = 1, EPI_ADDSCALE = 2 };

template <int EPI, int BM, int BN, bool OUTBF, bool VSPLIT>
__global__ __launch_bounds__(256, 4)
void mgemm(const u16* __restrict__ A1, int lda1, const u16* __restrict__ A2,
           int lda2, int ksplit, const u16* __restrict__ W1, int ldw1,
           const u16* __restrict__ W2, int ldw2, int woff2, int K,
           const float* __restrict__ bias, void* __restrict__ Cv, int ldc,
           const float* __restrict__ addsrc, u16* __restrict__ vt) {
  __shared__ u16 As[BM * 64];
  __shared__ u16 Bs[BN * 64];
  const int tid = threadIdx.x;
  const int w = tid >> 6, lane = tid & 63;
  const int ln = lane & 15, quad = lane >> 4;
  const int m0 = blockIdx.x * BM;
  const int n0 = blockIdx.y * BN;
  constexpr int MT = BM / 64;   // rows per wave = MT*16
  constexpr int NT = BN / 16;   // col fragments per wave
  const int wm = w * (MT * 16);
  constexpr int APW = BM / 64;

  f32x4 acc[MT][NT] = {};

  const int grow = lane >> 2;      // row within 16-row group
  const int gk8 = (lane & 3) * 8;  // k element offset

  for (int k0 = 0; k0 < K; k0 += 64) {
#pragma unroll
    for (int s = 0; s < 2; ++s) {
      const int kb = k0 + s * 32;
      const bool r1 = kb < ksplit;
      const u16* Ab = r1 ? A1 : A2;
      const int alda = r1 ? lda1 : lda2;
      const int ak = r1 ? kb : kb - ksplit;
#pragma unroll
      for (int p = 0; p < APW; ++p) {
        const int g = w * APW + p;
        glds16(Ab + (size_t)(m0 + g * 16 + grow) * alda + ak + gk8,
               As + s * BM * 32 + g * 512);
      }
      const u16* Wb = r1 ? W1 : W2;
      const int wlda = r1 ? ldw1 : ldw2;
      const int wk = r1 ? kb : kb - woff2;
      if (BN >= 64) {
#pragma unroll
        for (int p = 0; p < BN / 64; ++p) {
          const int g = w * (BN / 64) + p;
          glds16(Wb + (size_t)(n0 + g * 16 + grow) * wlda + wk + gk8,
                 Bs + s * BN * 32 + g * 512);
        }
      } else {
        if (w < BN / 16) {
          const int g = w;
          glds16(Wb + (size_t)(n0 + g * 16 + grow) * wlda + wk + gk8,
                 Bs + s * BN * 32 + g * 512);
        }
      }
    }
    __syncthreads();
#pragma unroll
    for (int s = 0; s < 2; ++s) {
      const u16* abase = As + s * BM * 32 + (wm >> 4) * 512 + ln * 32 + quad * 8;
      const u16* bbase = Bs + s * BN * 32 + ln * 32 + quad * 8;
      bf16x8 af[MT], bv[NT];
#pragma unroll
      for (int i = 0; i < MT; ++i) af[i] = *(const bf16x8*)(abase + i * 512);
#pragma unroll
      for (int j = 0; j < NT; ++j) bv[j] = *(const bf16x8*)(bbase + j * 512);
#pragma unroll
      for (int i = 0; i < MT; ++i)
#pragma unroll
        for (int j = 0; j < NT; ++j)
          acc[i][j] = __builtin_amdgcn_mfma_f32_16x16x32_bf16(af[i], bv[j],
                                                              acc[i][j], 0, 0, 0);
    }
    __syncthreads();
  }

#pragma unroll
  for (int i = 0; i < MT; ++i)
#pragma unroll
    for (int j = 0; j < NT; ++j) {
      const int col = n0 + j * 16 + ln;
      const float bsv = bias[col];
      const int row0 = m0 + wm + i * 16 + quad * 4;
      float vals[4];
#pragma unroll
      for (int r = 0; r < 4; ++r) {
        float v = acc[i][j][r] + bsv;
        if (EPI == EPI_GELU) v = 0.5f * v * (1.0f + erff(v * 0.70710678f));
        if (EPI == EPI_ADDSCALE)
          v = addsrc[(size_t)(row0 + r) * 256 + col] + 0.3f * v;
        vals[r] = v;
      }
      if (VSPLIT && col >= 512) {
        ushort4 pk;
        pk.x = f2bf(vals[0]); pk.y = f2bf(vals[1]);
        pk.z = f2bf(vals[2]); pk.w = f2bf(vals[3]);
        *(ushort4*)(vt + (size_t)((row0 >> 10) * 256 + (col - 512)) * T_SZ +
                    (row0 & 1023)) = pk;
      } else if (OUTBF) {
#pragma unroll
        for (int r = 0; r < 4; ++r)
          ((u16*)Cv)[(size_t)(row0 + r) * ldc + col] = f2bf(vals[r]);
      } else {
#pragma unroll
        for (int r = 0; r < 4; ++r)
          ((float*)Cv)[(size_t)(row0 + r) * ldc + col] = vals[r];
      }
    }
}

// ---------------------------------------------------------------------------
// Barrier-free MFMA flash attention (one wave = 16 q rows, paired balance).
// qk: [8192][512] bf16 (Q cols 0:256, K cols 256:512); vt transposed V.
// ---------------------------------------------------------------------------
__global__ __launch_bounds__(256)
void attn_flash(const u16* __restrict__ qk, const u16* __restrict__ vt,
                u16* __restrict__ outp) {
  __shared__ u16 Ps[4][16][72];
  const int tid = threadIdx.x;
  const int w = tid >> 6, lane = tid & 63;
  const int ln = lane & 15, quad = lane >> 4, kq8 = quad * 8;
  const int wu = blockIdx.x * 4 + w;
  const int bh = wu >> 6, s = wu & 63;
  const int qt = (s & 1) ? (63 - (s >> 1)) : (s >> 1);
  const int q0 = qt * 16;
  const int b = bh >> 2, h = bh & 3;
  const u16* base = qk + (size_t)b * T_SZ * 512;
  const u16* vbase = vt + (size_t)bh * 64 * T_SZ;

  bf16x8 qf[2];
#pragma unroll
  for (int ks = 0; ks < 2; ++ks)
    qf[ks] = *(const bf16x8*)(base + (size_t)(q0 + ln) * 512 + h * 64 +
                              ks * 32 + kq8);
  const short ob = (short)0x3F80;
  const bf16x8 ones = {ob, ob, ob, ob, ob, ob, ob, ob};

  f32x4 O[4] = {};
  f32x4 l_acc = {};
  const int ntiles = (qt >> 2) + 1;
  for (int jt = 0; jt < ntiles; ++jt) {
    const int c0 = jt * 64;
    f32x4 sv[4] = {};
#pragma unroll
    for (int ks = 0; ks < 2; ++ks)
#pragma unroll
      for (int j = 0; j < 4; ++j) {
        bf16x8 kf = *(const bf16x8*)(base + (size_t)(c0 + j * 16 + ln) * 512 +
                                     256 + h * 64 + ks * 32 + kq8);
        sv[j] = __builtin_amdgcn_mfma_f32_16x16x32_bf16(qf[ks], kf, sv[j], 0, 0, 0);
      }
    const bool need_mask = (c0 + 63 > q0);
#pragma unroll
    for (int j = 0; j < 4; ++j)
#pragma unroll
      for (int r = 0; r < 4; ++r) {
        float p = __expf(sv[j][r] * 0.125f);
        if (need_mask && (c0 + j * 16 + ln > q0 + quad * 4 + r)) p = 0.f;
        Ps[w][quad * 4 + r][j * 16 + ln] = f2bf(p);
      }
#pragma unroll
    for (int ks = 0; ks < 2; ++ks) {
      bf16x8 pf = *(const bf16x8*)&Ps[w][ln][ks * 32 + kq8];
      l_acc = __builtin_amdgcn_mfma_f32_16x16x32_bf16(pf, ones, l_acc, 0, 0, 0);
#pragma unroll
      for (int j = 0; j < 4; ++j) {
        bf16x8 vf = *(const bf16x8*)(vbase + (size_t)(j * 16 + ln) * T_SZ +
                                     c0 + ks * 32 + kq8);
        O[j] = __builtin_amdgcn_mfma_f32_16x16x32_bf16(pf, vf, O[j], 0, 0, 0);
      }
    }
  }
  u16* op = outp + (size_t)b * T_SZ * 256;
#pragma unroll
  for (int r = 0; r < 4; ++r) {
    const float inv = 1.f / l_acc[r];
#pragma unroll
    for (int j = 0; j < 4; ++j)
      op[(size_t)(q0 + quad * 4 + r) * 256 + h * 64 + j * 16 + ln] =
          f2bf(O[j][r] * inv);
  }
}

// ---------------------------------------------------------------------------
__device__ __forceinline__ float ln_finish(float v, float s1, float s2,
                                           float g, float bb) {
  float mean = s1 * (1.f / 256.f);
  float var = s2 * (1.f / 256.f) - mean * mean;
  return (v - mean) * rsqrtf(var + 1e-5f) * g + bb;
}

__global__ __launch_bounds__(256)
void ln_add_kernel(const float* __restrict__ a, const float* __restrict__ addsrc,
                   const float* __restrict__ g, const float* __restrict__ bb,
                   float* __restrict__ outp, u16* __restrict__ obf) {
  __shared__ float tmp[4];
  const size_t row = blockIdx.x;
  const int d = threadIdx.x;
  float v = a[row * 256 + d] + addsrc[row * 256 + d];
  float s1 = block_reduce_sum(v, tmp);
  float s2 = block_reduce_sum(v * v, tmp);
  float y = ln_finish(v, s1, s2, g[d], bb[d]);
  outp[row * 256 + d] = y;
  if (obf) obf[row * 256 + d] = f2bf(y);
}

// states = LN3(seq + 0.5*(local_cumsum + carry)) -> bf16; t==1023 also LN4.
__global__ __launch_bounds__(256)
void ln34_kernel(const float* __restrict__ deltas, const float* __restrict__ scr,
                 const float* __restrict__ seq, const float* __restrict__ g3,
                 const float* __restrict__ b3, const float* __restrict__ g4,
                 const float* __restrict__ b4, u16* __restrict__ st,
                 float* __restrict__ fss) {
  __shared__ float tmp[4];
  const int row = blockIdx.x;
  const int b = row >> 10, t = row & 1023;
  const int d = threadIdx.x;
  float v = seq[b * 256 + d] +
            0.5f * (deltas[(size_t)row * 256 + d] +
                    scr[(size_t)(b * 32 + (t >> 5)) * 256 + d]);
  float s1 = block_reduce_sum(v, tmp);
  float s2 = block_reduce_sum(v * v, tmp);
  float y = ln_finish(v, s1, s2, g3[d], b3[d]);
  st[(size_t)row * 256 + d] = f2bf(y);
  if (t == 1023) {
    float t1s = block_reduce_sum(y, tmp);
    float t2s = block_reduce_sum(y * y, tmp);
    fss[b * 256 + d] = ln_finish(y, t1s, t2s, g4[d], b4[d]);
  }
}

// ---------------------------------------------------------------------------
// Fused depthwise conv (window 8) + EMA local pass. comb [8192][512]:
// cols 0:256 conv, 256:512 local EMA.
// ---------------------------------------------------------------------------
__global__ __launch_bounds__(256)
void emaconv_kernel(const float* __restrict__ x, const float* __restrict__ cw,
                    const float* __restrict__ cb, u16* __restrict__ comb,
                    float* __restrict__ scr) {
  const int bc = blockIdx.x;
  const int b = bc >> 5, ch = bc & 31;
  const int d = threadIdx.x;
  const int t0 = ch * 32;
  float wreg[8];
#pragma unroll
  for (int j = 0; j < 8; ++j) wreg[j] = cw[d * 8 + j];
  const float bias = cb[d];
  float xw[8];
#pragma unroll
  for (int j = 0; j < 7; ++j) {
    const int ts = t0 - 7 + j;
    xw[j] = (ts >= 0) ? x[(size_t)(b * T_SZ + ts) * 256 + d] : 0.f;
  }
  float c = 0.f;
#pragma unroll
  for (int tl = 0; tl < 32; ++tl) {
    const size_t row = (size_t)(b * T_SZ + t0 + tl);
    xw[7] = x[row * 256 + d];
    float conv = bias;
#pragma unroll
    for (int j = 0; j < 8; ++j) conv = fmaf(xw[j], wreg[j], conv);
    c = 0.9f * c + 0.1f * xw[7];
    comb[row * 512 + d] = f2bf(conv);
    comb[row * 512 + 256 + d] = f2bf(c);
#pragma unroll
    for (int j = 0; j < 7; ++j) xw[j] = xw[j + 1];
  }
  scr[(size_t)bc * 256 + d] = c;
}

__global__ __launch_bounds__(256)
void ema_b_kernel(float* __restrict__ scr) {
  const int b = blockIdx.x, d = threadIdx.x;
  const float q32 = 0.03433683820292512f;  // 0.9^32
  float carry = 0.f;
  for (int ch = 0; ch < 32; ++ch) {
    const size_t idx = (size_t)(b * 32 + ch) * 256 + d;
    float e = scr[idx];
    scr[idx] = carry;
    carry = e + q32 * carry;
  }
}

__global__ __launch_bounds__(256)
void ema_c_kernel(u16* __restrict__ comb, const float* __restrict__ scr,
                  float* __restrict__ fts) {
  const int row = blockIdx.x;
  const int b = row >> 10, t = row & 1023;
  const int d = threadIdx.x;
  const int ch = t >> 5, tl = t & 31;
  float carry = scr[(size_t)(b * 32 + ch) * 256 + d];
  float l = bf2f(comb[(size_t)row * 512 + 256 + d]);
  float y = fmaf(__powf(0.9f, (float)(tl + 1)), carry, l);
  comb[(size_t)row * 512 + 256 + d] = f2bf(y);
  if (t == 1023) fts[b * 256 + d] = y;
}

__global__ __launch_bounds__(256)
void cs_a_kernel(float* __restrict__ deltas, float* __restrict__ scr) {
  const int bc = blockIdx.x;
  const int b = bc >> 5, ch = bc & 31;
  const int d = threadIdx.x;
  const int t0 = ch * 32;
  float c = 0.f;
  for (int tl = 0; tl < 32; ++tl) {
    const size_t idx = (size_t)(b * T_SZ + t0 + tl) * 256 + d;
    c += deltas[idx];
    deltas[idx] = c;
  }
  scr[(size_t)bc * 256 + d] = c;
}

__global__ __launch_bounds__(256)
void cs_b_kernel(float* __restrict__ scr) {
  const int b = blockIdx.x, d = threadIdx.x;
  float carry = 0.f;
  for (int ch = 0; ch < 32; ++ch) {
    const size_t idx = (size_t)(b * 32 + ch) * 256 + d;
    float e = scr[idx];
    scr[idx] = carry;
    carry += e;
  }
}

// ---------------------------------------------------------------------------
extern "C" void kernel_launch(void* const* d_in, const int* in_sizes, int n_in,
                              void* d_out, int out_size, void* d_ws,
                              size_t ws_size, hipStream_t stream) {
  (void)in_sizes; (void)n_in; (void)out_size; (void)ws_size;
  const float* parallel_repr = (const float*)d_in[0];
  const float* sequential_state = (const float*)d_in[1];
  const float* in_proj_b = (const float*)d_in[4];
  const float* out_proj_b = (const float*)d_in[6];
  const float* conv_w = (const float*)d_in[7];
  const float* conv_b = (const float*)d_in[8];
  const float* p2s_b = (const float*)d_in[10];
  const float* s2p_b = (const float*)d_in[12];
  const float* trans_b1 = (const float*)d_in[14];
  const float* trans_b2 = (const float*)d_in[16];
  const float* ffn_b1 = (const float*)d_in[18];
  const float* ffn_b2 = (const float*)d_in[20];
  const float* ln1_s = (const float*)d_in[21];
  const float* ln1_b = (const float*)d_in[22];
  const float* ln2_s = (const float*)d_in[23];
  const float* ln2_b = (const float*)d_in[24];
  const float* ln3_s = (const float*)d_in[25];
  const float* ln3_b = (const float*)d_in[26];
  const float* ln4_s = (const float*)d_in[27];
  const float* ln4_b = (const float*)d_in[28];

  char* ws = (char*)d_ws;
  u16* qk_bf = (u16*)(ws + OFF_QK);
  u16* vt = (u16*)(ws + OFF_VT);
  u16* attn_bf = (u16*)(ws + OFF_ATTN);
  float* x = (float*)(ws + OFF_X);
  u16* x_bf = (u16*)(ws + OFF_XBF);
  u16* comb = (u16*)(ws + OFF_COMB);
  u16* xp_bf = (u16*)(ws + OFF_XP);
  u16* h_bf = (u16*)(ws + OFF_H);
  float* fbuf = (float*)(ws + OFF_FB);
  u16* states_bf = (u16*)(ws + OFF_STATES);
  u16* ffn_in = (u16*)(ws + OFF_FFNIN);
  u16* f_bf = (u16*)(ws + OFF_F);
  u16* pr_bf = (u16*)(ws + OFF_PRBF);
  u16* wb = (u16*)(ws + OFF_WB);
  float* scr = (float*)(ws + OFF_SCR);
  float* out = (float*)d_out;
  float* out_fss = out + S_ELT;
  float* out_fts = out + S_ELT + 2048;

  const dim3 blk(256);

  // 0. weights + parallel_repr -> bf16
  wconv_kernel<<<3456, blk, 0, stream>>>(
      (const float*)d_in[3], (const float*)d_in[5], (const float*)d_in[9],
      (const float*)d_in[11], (const float*)d_in[13], (const float*)d_in[15],
      (const float*)d_in[17], (const float*)d_in[19], parallel_repr, wb, pr_bf);
  // 1. qkv projection: Q,K -> qk; V transposed -> vt  (1536 blocks)
  mgemm<EPI_NONE, 128, 32, true, true><<<dim3(64, 24), blk, 0, stream>>>(
      pr_bf, 256, pr_bf, 256, 256, wb + WB_INPROJ, 256, wb + WB_INPROJ, 256, 0,
      256, in_proj_b, qk_bf, 512, nullptr, vt);
  // 2. attention (barrier-free)
  attn_flash<<<512, blk, 0, stream>>>(qk_bf, vt, attn_bf);
  // 3. attn_out = attn @ out_proj^T + b -> fbuf (fp32)  (1024 blocks)
  mgemm<EPI_NONE, 64, 32, false, false><<<dim3(128, 8), blk, 0, stream>>>(
      attn_bf, 256, attn_bf, 256, 256, wb + WB_OUTPROJ, 256, wb + WB_OUTPROJ,
      256, 0, 256, out_proj_b, fbuf, 256, nullptr, nullptr);
  // 4. x = LN1(PR + attn_out), also emit x_bf
  ln_add_kernel<<<8192, blk, 0, stream>>>(parallel_repr, fbuf, ln1_s, ln1_b, x,
                                          x_bf);
  // 5-7. fused conv+EMA -> comb + traj summary
  emaconv_kernel<<<256, blk, 0, stream>>>(x, conv_w, conv_b, comb, scr);
  ema_b_kernel<<<8, blk, 0, stream>>>(scr);
  ema_c_kernel<<<8192, blk, 0, stream>>>(comb, scr, out_fts);
  // 8. xp = x + 0.3*(x @ p2s^T + b)  -> bf16  (1024 blocks)
  mgemm<EPI_ADDSCALE, 64, 32, true, false><<<dim3(128, 8), blk, 0, stream>>>(
      x_bf, 256, x_bf, 256, 256, wb + WB_P2S, 256, wb + WB_P2S, 256, 0, 256,
      p2s_b, xp_bf, 256, x, nullptr);
  // 9. h = gelu([xp | conv | ema] @ t1^T + b1)  (split-A, K=768, 1024 blocks)
  mgemm<EPI_GELU, 128, 32, true, false><<<dim3(64, 16), blk, 0, stream>>>(
      xp_bf, 256, comb, 512, 256, wb + WB_T1, 768, wb + WB_T1, 768, 0, 768,
      trans_b1, h_bf, 512, nullptr, nullptr);
  // 10. deltas = h @ t2^T + b2 -> fbuf (fp32)  (1024 blocks)
  mgemm<EPI_NONE, 64, 32, false, false><<<dim3(128, 8), blk, 0, stream>>>(
      h_bf, 512, h_bf, 512, 512, wb + WB_T2, 512, wb + WB_T2, 512, 0, 512,
      trans_b2, fbuf, 256, nullptr, nullptr);
  // 11-12. chunked cumsum
  cs_a_kernel<<<256, blk, 0, stream>>>(fbuf, scr);
  cs_b_kernel<<<8, blk, 0, stream>>>(scr);
  // 13. states = LN3(...) -> bf16; fused LN4 -> out_fss
  ln34_kernel<<<8192, blk, 0, stream>>>(fbuf, scr, sequential_state, ln3_s,
                                        ln3_b, ln4_s, ln4_b, states_bf, out_fss);
  // 14. ffn_in = x + 0.3*(states @ s2p^T + b) -> bf16  (1024 blocks)
  mgemm<EPI_ADDSCALE, 64, 32, true, false><<<dim3(128, 8), blk, 0, stream>>>(
      states_bf, 256, states_bf, 256, 256, wb + WB_S2P, 256, wb + WB_S2P, 256,
      0, 256, s2p_b, ffn_in, 256, x, nullptr);
  // 15. f = gelu(ffn_in @ ffn1^T + b1)  (1024 blocks)
  mgemm<EPI_GELU, 128, 64, true, false><<<dim3(64, 16), blk, 0, stream>>>(
      ffn_in, 256, ffn_in, 256, 256, wb + WB_F1, 256, wb + WB_F1, 256, 0, 256,
      ffn_b1, f_bf, 1024, nullptr, nullptr);
  // 16. ffn_out = f @ ffn2^T + b2 -> fbuf  (1024 blocks)
  mgemm<EPI_NONE, 64, 32, false, false><<<dim3(128, 8), blk, 0, stream>>>(
      f_bf, 1024, f_bf, 1024, 1024, wb + WB_F2, 1024, wb + WB_F2, 1024, 0,
      1024, ffn_b2, fbuf, 256, nullptr, nullptr);
  // 17. out = LN2(x + ffn_out)
  ln_add_kernel<<<8192, blk, 0, stream>>>(x, fbuf, ln2_s, ln2_b, out, nullptr);
}